// Round 2
// 199.156 us; speedup vs baseline: 1.0254x; 1.0254x over previous
//
#include <hip/hip_runtime.h>
#include <hip/hip_bf16.h>

typedef __hip_bfloat16 bf16;
typedef __attribute__((ext_vector_type(8))) short bf16x8;
typedef __attribute__((ext_vector_type(4))) float f32x4;

#define BT     3200
#define N_     22
#define NO     1408           // N_*64
#define NN     484
#define BTN    70400
#define ELEMS  4505600        // BT*N_*64
#define MAXNZ  128
#define NSHARD 16

static __device__ __forceinline__ bf16  f2bf(float v) { return __float2bfloat16(v); }
static __device__ __forceinline__ short fbf(float v) {
    bf16 h = __float2bfloat16(v);
    return *reinterpret_cast<short*>(&h);
}
static __device__ __forceinline__ float sbf(short s) {
    return __uint_as_float(((unsigned)(unsigned short)s) << 16);
}
static __device__ __forceinline__ void unp(unsigned u, float& lo, float& hi) {
    lo = __uint_as_float(u << 16);
    hi = __uint_as_float(u & 0xffff0000u);
}

// ---------------------------------------------------------------------------
// Kernel 1 (prep): blocks 0-1 AA softmax; 2-7 CB; 8-17 WB;
// 18: per-row off-diag edge bitmaps + att MFMA A-fragments (bf16).
// ---------------------------------------------------------------------------
__global__ void prep_kernel(const float* __restrict__ e_s, const int* __restrict__ rs,
                            const int* __restrict__ cs, int nnz_s,
                            const float* __restrict__ e_c, const int* __restrict__ rc,
                            const int* __restrict__ cc, int nnz_c,
                            const float* __restrict__ cat_w,
                            const float* __restrict__ Wsym, const float* __restrict__ Wcon,
                            const float* __restrict__ Wdis, const float* __restrict__ att,
                            short* __restrict__ AAb, short* __restrict__ CB,
                            short* __restrict__ WB, int* __restrict__ bm,
                            short* __restrict__ attF) {
    const int tid = threadIdx.x;
    if (blockIdx.x < 2) {
        __shared__ float eL[64 * (MAXNZ + 1)];
        __shared__ int rowsL[MAXNZ], colsL[MAXNZ];
        const int t = blockIdx.x;
        const float* e    = t ? e_c : e_s;
        const int*   rows = t ? rc  : rs;
        const int*   cols = t ? cc  : cs;
        const int    nnz  = t ? nnz_c : nnz_s;
        const int    str  = nnz + 1;

        for (int idx = tid; idx < 64 * nnz; idx += 256) {
            int o = idx / nnz, k = idx - o * nnz;
            eL[o * str + k] = expf(e[idx]);
        }
        for (int idx = tid; idx < nnz; idx += 256) { rowsL[idx] = rows[idx]; colsL[idx] = cols[idx]; }
        __syncthreads();

        const int o = tid & 63, ig = tid >> 6;
        float s[6];
        #pragma unroll
        for (int q = 0; q < 6; q++) s[q] = 0.f;
        for (int k = 0; k < nnz; k++) {
            int r = rowsL[k];
            float ev = eL[o * str + k];
            #pragma unroll
            for (int q = 0; q < 6; q++)
                if (r == ig + 4 * q) s[q] += ev;
        }
        float inv[6];
        #pragma unroll
        for (int q = 0; q < 6; q++) inv[q] = 1.f / s[q];
        for (int k = 0; k < nnz; k++) {
            int r = rowsL[k];
            #pragma unroll
            for (int q = 0; q < 6; q++)
                if (r == ig + 4 * q)
                    AAb[((size_t)(r * N_ + colsL[k]) * 64 + o) * 2 + t] =
                        fbf(eL[o * str + k] * inv[q]);
        }
    } else if (blockIdx.x < 8) {
        int gi = (blockIdx.x - 2) * 256 + tid;
        if (gi >= 1536) return;
        int nt = gi / 384, rem = gi % 384;
        int kc = rem >> 6, L = rem & 63;
        int n = nt * 16 + (L & 15);
        int kbase = kc * 32 + (L >> 4) * 8;
        float4 w0 = *(const float4*)&cat_w[n * 192 + kbase];
        float4 w1 = *(const float4*)&cat_w[n * 192 + kbase + 4];
        bf16x8 frag;
        frag[0] = fbf(w0.x); frag[1] = fbf(w0.y); frag[2] = fbf(w0.z); frag[3] = fbf(w0.w);
        frag[4] = fbf(w1.x); frag[5] = fbf(w1.y); frag[6] = fbf(w1.z); frag[7] = fbf(w1.w);
        ((bf16x8*)CB)[gi] = frag;
    } else if (blockIdx.x < 18) {
        int gi = (blockIdx.x - 8) * 256 + tid;
        if (gi >= 2560) return;
        int L = gi & 63;
        int q = gi >> 6;
        int nt = q & 3;
        int pk = q >> 2;
        int kc = pk & 1;
        int p  = pk >> 1;
        const float* Wsrc = (p == 0) ? Wsym :
                            (p == 1) ? Wsym + 4096 :
                            (p == 2) ? Wcon :
                            (p == 3) ? Wcon + 4096 : Wdis;
        int n  = nt * 16 + (L & 15);
        int kb = kc * 32 + (L >> 4) * 8;
        bf16x8 frag;
        #pragma unroll
        for (int j = 0; j < 8; j++) frag[j] = fbf(Wsrc[(kb + j) * 64 + n]);
        ((bf16x8*)WB)[gi] = frag;
    } else {
        // edge bitmaps (off-diagonal union of sym+con) -- exact nnz pattern
        if (tid < N_) {
            unsigned bits = 0u;
            for (int e = 0; e < nnz_s; e++)
                if (rs[e] == tid && cs[e] != tid) bits |= 1u << cs[e];
            for (int e = 0; e < nnz_c; e++)
                if (rc[e] == tid && cc[e] != tid) bits |= 1u << cc[e];
            bm[tid] = (int)bits;
        }
        // att A-fragments: A[m][k] = att[m][k] for m,k<22 else 0 (M=32 pad, K=32 pad)
        for (int f = tid; f < 128; f += 256) {
            int rt = f >> 6, LL = f & 63;
            int row = rt * 16 + (LL & 15);
            int kb  = (LL >> 4) * 8;
            bf16x8 frag;
            #pragma unroll
            for (int j = 0; j < 8; j++) {
                int k = kb + j;
                float vv = (row < N_ && k < N_) ? att[row * N_ + k] : 0.f;
                frag[j] = fbf(vv);
            }
            ((bf16x8*)attF)[f] = frag;
        }
    }
}

// ---------------------------------------------------------------------------
// Kernel 2: FUSED x-stage + h-GEMM + sparse mixer + z-MFMA. 1 bt per block,
// grid 3200. Phases:
//  (a) load x rows, per-channel S/S2 reduce, write swizzled bf16 xl/dl tiles
//  (b) 5-plane MFMA GEMM (20 MFMA/wave) from LDS A-frags + WB B-frags
//  (c) epilogue packs pp0={h1s|h0s}, pp1={h1c|h0c}, p2=hdw
//      NOTE: high halves hold h0 (NOT h0-h1) because the sparse mixer below
//      excludes the diagonal from its edge sum; diag term = A[i,i]*h0[i].
//  (d) z = att @ hdw via 2 MFMAs (attF A-frags, p2 B-frags)
//  (e) sym/con mixing over edge bitmaps only (softmax(A) is exactly 0 off-edge)
// ---------------------------------------------------------------------------
__launch_bounds__(256)
__global__ void fused_hmix(const float* __restrict__ x, const short* __restrict__ WB,
                           const short* __restrict__ AAb, const short* __restrict__ attF,
                           const int* __restrict__ bm, const float* __restrict__ bdis,
                           bf16* __restrict__ xs, bf16* __restrict__ yc,
                           bf16* __restrict__ z, float* __restrict__ stats1) {
    __shared__ __align__(16) char smem[14080];
    short*    xl   = (short*)smem;                 // [32][64] bf16, XOR-swizzled
    short*    dl   = (short*)(smem + 4096);
    float*    red4 = (float*)(smem + 8192);        // 512 f32 (dead before GEMM ends)
    unsigned* pp0  = (unsigned*)smem;              // [22][64] (after GEMM)
    unsigned* pp1  = (unsigned*)(smem + 5632);
    short*    p2   = (short*)(smem + 11264);       // [22][64]
    float*    red  = (float*)smem;                 // stats scratch (post-mixing)

    const int g   = blockIdx.x;
    const int tid = threadIdx.x;
    const size_t base = (size_t)g * NO;
    const int w = tid >> 6, L = tid & 63;
    const int lane16 = L & 15, quad = L >> 4;
    const int colw = w * 16 + lane16;
    const bf16x8* WBf = (const bf16x8*)WB;

    // ---- (a) stage x + distance stats (was pre_pass)
    float v[6], s = 0.f, s2 = 0.f;
    #pragma unroll
    for (int k = 0; k < 6; k++) {
        int i = w + 4 * k;
        float t = (i < N_) ? x[base + i * 64 + L] : 0.f;
        v[k] = t; s += t; s2 += t * t;
    }
    red4[w * 64 + L]       = s;
    red4[256 + w * 64 + L] = s2;
    for (int idx = tid; idx < 320; idx += 256) {   // zero pad rows 22..31
        ((unsigned*)xl)[704 + idx] = 0u;
        ((unsigned*)dl)[704 + idx] = 0u;
    }
    __syncthreads();
    float S  = (red4[L] + red4[64 + L]) + (red4[128 + L] + red4[192 + L]);
    float S2 = (red4[256 + L] + red4[320 + L]) + (red4[384 + L] + red4[448 + L]);
    #pragma unroll
    for (int k = 0; k < 6; k++) {
        int i = w + 4 * k;
        if (i < N_) {
            float t = v[k];
            float d2 = S2 - 2.f * t * S + (float)N_ * t * t;
            float d  = sqrtf(fmaxf(d2, 0.f)) + 1e-8f;
            int ci = i * 64 + (L ^ ((i & 7) << 3));
            xl[ci] = fbf(t);
            dl[ci] = fbf(d);
        }
    }
    __syncthreads();

    // ---- (b) GEMM: 5 planes x 2 row-tiles x 2 k-chunks
    f32x4 acc[5][2];
    #pragma unroll
    for (int p = 0; p < 5; p++)
        #pragma unroll
        for (int rt = 0; rt < 2; rt++) acc[p][rt] = (f32x4){0.f, 0.f, 0.f, 0.f};

    #pragma unroll
    for (int kc = 0; kc < 2; kc++) {
        bf16x8 ax[2], ad[2];
        #pragma unroll
        for (int rt = 0; rt < 2; rt++) {
            int row = rt * 16 + lane16;
            int ci  = row * 64 + ((kc * 32 + quad * 8) ^ ((row & 7) << 3));
            ax[rt] = *(const bf16x8*)(xl + ci);
            ad[rt] = *(const bf16x8*)(dl + ci);
        }
        #pragma unroll
        for (int p = 0; p < 5; p++) {
            bf16x8 bw = WBf[((p * 2 + kc) * 4 + w) * 64 + L];
            #pragma unroll
            for (int rt = 0; rt < 2; rt++) {
                bf16x8 a = (p < 4) ? ax[rt] : ad[rt];
                acc[p][rt] = __builtin_amdgcn_mfma_f32_16x16x32_bf16(a, bw, acc[p][rt], 0, 0, 0);
            }
        }
    }
    __syncthreads();   // xl/dl reads done before pp overwrite

    // ---- (c) epilogue pack -> LDS (high halves = h0, see kernel comment)
    #pragma unroll
    for (int rt = 0; rt < 2; rt++)
        #pragma unroll
        for (int r = 0; r < 4; r++) {
            int m = rt * 16 + quad * 4 + r;
            if (m < N_) {
                float h0s = acc[0][rt][r], h1s = acc[1][rt][r];
                float h0c = acc[2][rt][r], h1c = acc[3][rt][r];
                pp0[m * 64 + colw] = (unsigned)(unsigned short)fbf(h1s) |
                                     ((unsigned)(unsigned short)fbf(h0s) << 16);
                pp1[m * 64 + colw] = (unsigned)(unsigned short)fbf(h1c) |
                                     ((unsigned)(unsigned short)fbf(h0c) << 16);
                p2[m * 64 + colw] = fbf(acc[4][rt][r]);
            }
        }
    __syncthreads();

    // ---- (d) z = att @ hdw via MFMA (K=32 pad, rows >=22 masked to 0)
    f32x4 zacc[2];
    zacc[0] = (f32x4){0.f, 0.f, 0.f, 0.f};
    zacc[1] = (f32x4){0.f, 0.f, 0.f, 0.f};
    {
        bf16x8 bfrag;
        #pragma unroll
        for (int j = 0; j < 8; j++) {
            int k = quad * 8 + j;
            bfrag[j] = (k < N_) ? p2[k * 64 + colw] : (short)0;
        }
        const bf16x8* attFf = (const bf16x8*)attF;
        #pragma unroll
        for (int rt = 0; rt < 2; rt++)
            zacc[rt] = __builtin_amdgcn_mfma_f32_16x16x32_bf16(attFf[rt * 64 + L], bfrag,
                                                               zacc[rt], 0, 0, 0);
    }

    // ---- (e) sparse sym/con mixing over edge bitmaps
    float mxs[6], myc[6];
    #pragma unroll
    for (int k = 0; k < 6; k++) { mxs[k] = 0.f; myc[k] = 0.f; }
    const unsigned* AAu = (const unsigned*)AAb;
    #pragma unroll
    for (int k = 0; k < 6; k++) {
        int i = w + 4 * k;
        if (i < N_) {
            unsigned bits = (unsigned)bm[i];
            while (bits) {
                int j = __ffs(bits) - 1;
                bits &= bits - 1;
                unsigned a = AAu[(size_t)(i * N_ + j) * 64 + L];
                float as, ac; unp(a, as, ac);
                float h1s = sbf((short)pp0[j * 64 + L]);
                float h1c = sbf((short)pp1[j * 64 + L]);
                mxs[k] = fmaf(as, h1s, mxs[k]);
                myc[k] = fmaf(ac, h1c, myc[k]);
            }
        }
    }

    // ---- outputs + stats: xs/yc (channel = L); diag term = A[i,i]*h0[i]
    float st0 = 0.f, st1 = 0.f, st2 = 0.f, st3 = 0.f;
    #pragma unroll
    for (int k = 0; k < 6; k++) {
        int i = w + 4 * k;
        if (i < N_) {
            unsigned ad2 = AAu[(size_t)(i * 23) * 64 + L];
            float asd, acd; unp(ad2, asd, acd);
            float h0sv = __uint_as_float(pp0[i * 64 + L] & 0xffff0000u);
            float h0cv = __uint_as_float(pp1[i * 64 + L] & 0xffff0000u);
            float xsv = mxs[k] + asd * h0sv;
            float ycv = myc[k] + acd * h0cv;
            size_t oi = base + i * 64 + L;
            xs[oi] = f2bf(xsv); yc[oi] = f2bf(ycv);
            st0 += xsv; st1 += xsv * xsv;
            st2 += ycv; st3 += ycv * ycv;
        }
    }

    // z outputs + stats (channel = colw)
    float bd = bdis[colw];
    float st4 = 0.f, st5 = 0.f;
    #pragma unroll
    for (int rt = 0; rt < 2; rt++)
        #pragma unroll
        for (int r = 0; r < 4; r++) {
            int m = rt * 16 + quad * 4 + r;
            if (m < N_) {
                float zv = zacc[rt][r] + bd;
                z[base + (size_t)m * 64 + colw] = f2bf(zv);
                st4 += zv; st5 += zv * zv;
            }
        }
    st4 += __shfl_xor(st4, 16); st4 += __shfl_xor(st4, 32);
    st5 += __shfl_xor(st5, 16); st5 += __shfl_xor(st5, 32);

    __syncthreads();               // all pp/p2 reads done; reuse as red
    red[(w * 4 + 0) * 64 + L] = st0;
    red[(w * 4 + 1) * 64 + L] = st1;
    red[(w * 4 + 2) * 64 + L] = st2;
    red[(w * 4 + 3) * 64 + L] = st3;
    if (quad == 0) { red[16 * 64 + colw] = st4; red[17 * 64 + colw] = st5; }
    __syncthreads();
    float* myStats = stats1 + (size_t)(g & (NSHARD - 1)) * 384;
    for (int qq = tid; qq < 384; qq += 256) {
        int q = qq >> 6, o = qq & 63;
        float vv;
        if (q < 4)
            vv = (red[q * 64 + o] + red[(4 + q) * 64 + o]) +
                 (red[(8 + q) * 64 + o] + red[(12 + q) * 64 + o]);
        else
            vv = red[(12 + q) * 64 + o];   // q=4 -> row16, q=5 -> row17
        atomicAdd(&myStats[qq], vv);
    }
}

// ---------------------------------------------------------------------------
// Kernel 3: BN affine from (sharded) atomic stats (verified, unchanged).
// ---------------------------------------------------------------------------
__global__ void scale_from_stats(const float* __restrict__ stats,
                                 const float* __restrict__ gammas,
                                 const float* __restrict__ betas,
                                 int nch, int gbase, int nshard, int sstride,
                                 float* __restrict__ scale) {
    int tid = threadIdx.x;
    if (tid >= nch * 64) return;
    int t = tid >> 6, o = tid & 63;
    float S = 0.f, SS = 0.f;
    for (int s = 0; s < nshard; s++) {
        S  += stats[s * sstride + (2 * t) * 64 + o];
        SS += stats[s * sstride + (2 * t + 1) * 64 + o];
    }
    const float invn = 1.f / (float)BTN;
    float mu   = S * invn;
    float var  = SS * invn - mu * mu;
    float rstd = rsqrtf(var + 1e-5f);
    float a = gammas[(gbase + t) * 64 + o] * rstd;
    float c = betas[(gbase + t) * 64 + o] - mu * a;
    scale[t * 128 + o]      = a;
    scale[t * 128 + 64 + o] = c;
}

// ---------------------------------------------------------------------------
// Kernel 4: mix GEMM (verified, unchanged).
// ---------------------------------------------------------------------------
__launch_bounds__(256)
__global__ void mix_pass(const bf16* __restrict__ xs, const bf16* __restrict__ yc,
                         const bf16* __restrict__ z, const float* __restrict__ scale1,
                         const short* __restrict__ CB,
                         bf16* __restrict__ out2, float* __restrict__ stats2) {
    __shared__ float sL[384];
    __shared__ float red[512];

    const int tid = threadIdx.x;
    const int w = tid >> 6, L = tid & 63;
    const int lane16 = L & 15, quad = L >> 4;
    const int R0 = blockIdx.x * 128 + w * 32;

    for (int idx = tid; idx < 384; idx += 256) sL[idx] = scale1[idx];
    __syncthreads();

    const bf16* srcs[3] = { xs, yc, z };

    f32x4 acc[2][4];
    #pragma unroll
    for (int rt = 0; rt < 2; rt++)
        #pragma unroll
        for (int nt = 0; nt < 4; nt++)
            acc[rt][nt] = (f32x4){0.f, 0.f, 0.f, 0.f};

    #pragma unroll
    for (int kc = 0; kc < 6; kc++) {
        const int src = kc >> 1;
        const int c0  = (kc & 1) * 32 + quad * 8;
        bf16x8 av[2];
        #pragma unroll
        for (int rt = 0; rt < 2; rt++) {
            int row = R0 + rt * 16 + lane16;
            uint4 u = *(const uint4*)(srcs[src] + (size_t)row * 64 + c0);
            float v[8];
            unp(u.x, v[0], v[1]); unp(u.y, v[2], v[3]);
            unp(u.z, v[4], v[5]); unp(u.w, v[6], v[7]);
            #pragma unroll
            for (int e = 0; e < 8; e++) {
                float t = fmaxf(fmaf(v[e], sL[src * 128 + c0 + e],
                                     sL[src * 128 + 64 + c0 + e]), 0.f);
                av[rt][e] = fbf(t);
            }
        }
        #pragma unroll
        for (int nt = 0; nt < 4; nt++) {
            bf16x8 bw = ((const bf16x8*)CB)[(nt * 6 + kc) * 64 + L];
            acc[0][nt] = __builtin_amdgcn_mfma_f32_16x16x32_bf16(av[0], bw, acc[0][nt], 0, 0, 0);
            acc[1][nt] = __builtin_amdgcn_mfma_f32_16x16x32_bf16(av[1], bw, acc[1][nt], 0, 0, 0);
        }
    }

    float s[4]  = {0.f, 0.f, 0.f, 0.f};
    float s2[4] = {0.f, 0.f, 0.f, 0.f};
    #pragma unroll
    for (int rt = 0; rt < 2; rt++)
        #pragma unroll
        for (int nt = 0; nt < 4; nt++)
            #pragma unroll
            for (int r = 0; r < 4; r++) {
                int row = R0 + rt * 16 + quad * 4 + r;
                int col = nt * 16 + lane16;
                float v = acc[rt][nt][r];
                out2[(size_t)row * 64 + col] = f2bf(v);
                s[nt] += v; s2[nt] += v * v;
            }
    #pragma unroll
    for (int nt = 0; nt < 4; nt++) {
        s[nt]  += __shfl_xor(s[nt], 16);
        s[nt]  += __shfl_xor(s[nt], 32);
        s2[nt] += __shfl_xor(s2[nt], 16);
        s2[nt] += __shfl_xor(s2[nt], 32);
    }
    if (quad == 0) {
        #pragma unroll
        for (int nt = 0; nt < 4; nt++) {
            red[w * 64 + nt * 16 + lane16]       = s[nt];
            red[256 + w * 64 + nt * 16 + lane16] = s2[nt];
        }
    }
    __syncthreads();
    if (tid < 64) {
        float t = red[tid] + red[64 + tid] + red[128 + tid] + red[192 + tid];
        atomicAdd(&stats2[tid], t);
    } else if (tid < 128) {
        int c = tid - 64;
        float t = red[256 + c] + red[320 + c] + red[384 + c] + red[448 + c];
        atomicAdd(&stats2[64 + c], t);
    }
}

// ---------------------------------------------------------------------------
// Kernel 5: final BN + ReLU + f32 store (verified, unchanged).
// ---------------------------------------------------------------------------
__global__ void final_pass(const bf16* __restrict__ out2, const float* __restrict__ scale2,
                           float* __restrict__ out) {
    const int gid = blockIdx.x * 256 + threadIdx.x;
    const int idx = gid * 4;
    ushort4 u = reinterpret_cast<const ushort4*>(out2)[gid];
    const int o = idx & 63;
    float f0, f1, f2, f3;
    unp((unsigned)u.x | ((unsigned)u.y << 16), f0, f1);
    unp((unsigned)u.z | ((unsigned)u.w << 16), f2, f3);
    float4 r;
    r.x = fmaxf(fmaf(f0, scale2[o],     scale2[64 + o]),     0.f);
    r.y = fmaxf(fmaf(f1, scale2[o + 1], scale2[64 + o + 1]), 0.f);
    r.z = fmaxf(fmaf(f2, scale2[o + 2], scale2[64 + o + 2]), 0.f);
    r.w = fmaxf(fmaf(f3, scale2[o + 3], scale2[64 + o + 3]), 0.f);
    reinterpret_cast<float4*>(out)[gid] = r;
}

// ---------------------------------------------------------------------------
extern "C" void kernel_launch(void* const* d_in, const int* in_sizes, int n_in,
                              void* d_out, int out_size, void* d_ws, size_t ws_size,
                              hipStream_t stream) {
    const float* x      = (const float*)d_in[0];
    const float* W_sym  = (const float*)d_in[1];
    const float* e_sym  = (const float*)d_in[2];
    const float* W_con  = (const float*)d_in[3];
    const float* e_con  = (const float*)d_in[4];
    const float* W_dis  = (const float*)d_in[5];
    const float* att    = (const float*)d_in[6];
    const float* b_dis  = (const float*)d_in[7];
    const float* cat_w  = (const float*)d_in[8];
    const float* gammas = (const float*)d_in[9];
    const float* betas  = (const float*)d_in[10];
    const int* rows_sym = (const int*)d_in[11];
    const int* cols_sym = (const int*)d_in[12];
    const int* rows_con = (const int*)d_in[13];
    const int* cols_con = (const int*)d_in[14];
    const int nnz_s = in_sizes[2] / 64;
    const int nnz_c = in_sizes[4] / 64;

    char* p = (char*)d_ws;
    float* stats  = (float*)p; p += (NSHARD * 384 + 128) * 4;
    float* scale1 = (float*)p; p += 384 * 4;
    float* scale2 = (float*)p; p += 128 * 4;
    short* AAb    = (short*)p; p += (size_t)NN * 64 * 2 * 2;
    short* CB     = (short*)p; p += (size_t)1536 * 8 * 2;
    short* WB     = (short*)p; p += (size_t)2560 * 8 * 2;
    int*   bm     = (int*)p;   p += 128;
    short* attF   = (short*)p; p += 128 * 16;
    bf16*  xsb    = (bf16*)p;  p += (size_t)ELEMS * 2;
    bf16*  ycb    = (bf16*)p;  p += (size_t)ELEMS * 2;
    bf16*  zb     = (bf16*)p;  p += (size_t)ELEMS * 2;
    bf16*  out2   = (bf16*)p;  p += (size_t)ELEMS * 2;
    float* stats1 = stats;
    float* stats2 = stats + NSHARD * 384;

    hipMemsetAsync(stats, 0, (NSHARD * 384 + 128) * 4, stream);
    hipMemsetAsync(AAb, 0, (size_t)NN * 64 * 2 * 2, stream);
    prep_kernel<<<19, 256, 0, stream>>>(e_sym, rows_sym, cols_sym, nnz_s,
                                        e_con, rows_con, cols_con, nnz_c,
                                        cat_w, W_sym, W_con, W_dis, att,
                                        AAb, CB, WB, bm, attF);
    fused_hmix<<<BT, 256, 0, stream>>>(x, WB, AAb, attF, bm, b_dis,
                                       xsb, ycb, zb, stats1);
    scale_from_stats<<<1, 192, 0, stream>>>(stats1, gammas, betas, 3, 0, NSHARD, 384, scale1);
    mix_pass<<<550, 256, 0, stream>>>(xsb, ycb, zb, scale1, CB, out2, stats2);
    scale_from_stats<<<1, 64, 0, stream>>>(stats2, gammas, betas, 1, 3, 1, 0, scale2);
    final_pass<<<ELEMS / 1024, 256, 0, stream>>>(out2, scale2, (float*)d_out);
}

// Round 3
// 172.628 us; speedup vs baseline: 1.1830x; 1.1537x over previous
//
#include <hip/hip_runtime.h>
#include <hip/hip_bf16.h>

typedef __hip_bfloat16 bf16;
typedef __attribute__((ext_vector_type(8))) short bf16x8;
typedef __attribute__((ext_vector_type(4))) float f32x4;

#define BT     3200
#define N_     22
#define NO     1408           // N_*64
#define NN     484
#define BTN    70400
#define ELEMS  4505600        // BT*N_*64
#define MAXNZ  128
#define NSHARD 16
#define STATSZ (NSHARD * 384 + 8 * 128)

static __device__ __forceinline__ bf16  f2bf(float v) { return __float2bfloat16(v); }
static __device__ __forceinline__ short fbf(float v) {
    bf16 h = __float2bfloat16(v);
    return *reinterpret_cast<short*>(&h);
}
static __device__ __forceinline__ float sbf(short s) {
    return __uint_as_float(((unsigned)(unsigned short)s) << 16);
}
static __device__ __forceinline__ void unp(unsigned u, float& lo, float& hi) {
    lo = __uint_as_float(u << 16);
    hi = __uint_as_float(u & 0xffff0000u);
}

// ---------------------------------------------------------------------------
// Kernel 1 (prep): blocks 0-1 AA softmax; 2-7 CB; 8-17 WB;
// 18: stats zero + padded edge j-lists (8/row, zero-weight sentinel) + attF.
// ---------------------------------------------------------------------------
__global__ void prep_kernel(const float* __restrict__ e_s, const int* __restrict__ rs,
                            const int* __restrict__ cs, int nnz_s,
                            const float* __restrict__ e_c, const int* __restrict__ rc,
                            const int* __restrict__ cc, int nnz_c,
                            const float* __restrict__ cat_w,
                            const float* __restrict__ Wsym, const float* __restrict__ Wcon,
                            const float* __restrict__ Wdis, const float* __restrict__ att,
                            short* __restrict__ AAb, short* __restrict__ CB,
                            short* __restrict__ WB, int* __restrict__ ej,
                            short* __restrict__ attF, float* __restrict__ stats) {
    const int tid = threadIdx.x;
    if (blockIdx.x < 2) {
        __shared__ float eL[64 * (MAXNZ + 1)];
        __shared__ int rowsL[MAXNZ], colsL[MAXNZ];
        const int t = blockIdx.x;
        const float* e    = t ? e_c : e_s;
        const int*   rows = t ? rc  : rs;
        const int*   cols = t ? cc  : cs;
        const int    nnz  = t ? nnz_c : nnz_s;
        const int    str  = nnz + 1;

        for (int idx = tid; idx < 64 * nnz; idx += 256) {
            int o = idx / nnz, k = idx - o * nnz;
            eL[o * str + k] = expf(e[idx]);
        }
        for (int idx = tid; idx < nnz; idx += 256) { rowsL[idx] = rows[idx]; colsL[idx] = cols[idx]; }
        __syncthreads();

        const int o = tid & 63, ig = tid >> 6;
        float s[6];
        #pragma unroll
        for (int q = 0; q < 6; q++) s[q] = 0.f;
        for (int k = 0; k < nnz; k++) {
            int r = rowsL[k];
            float ev = eL[o * str + k];
            #pragma unroll
            for (int q = 0; q < 6; q++)
                if (r == ig + 4 * q) s[q] += ev;
        }
        float inv[6];
        #pragma unroll
        for (int q = 0; q < 6; q++) inv[q] = 1.f / s[q];
        for (int k = 0; k < nnz; k++) {
            int r = rowsL[k];
            #pragma unroll
            for (int q = 0; q < 6; q++)
                if (r == ig + 4 * q)
                    AAb[((size_t)(r * N_ + colsL[k]) * 64 + o) * 2 + t] =
                        fbf(eL[o * str + k] * inv[q]);
        }
    } else if (blockIdx.x < 8) {
        int gi = (blockIdx.x - 2) * 256 + tid;
        if (gi >= 1536) return;
        int nt = gi / 384, rem = gi % 384;
        int kc = rem >> 6, L = rem & 63;
        int n = nt * 16 + (L & 15);
        int kbase = kc * 32 + (L >> 4) * 8;
        float4 w0 = *(const float4*)&cat_w[n * 192 + kbase];
        float4 w1 = *(const float4*)&cat_w[n * 192 + kbase + 4];
        bf16x8 frag;
        frag[0] = fbf(w0.x); frag[1] = fbf(w0.y); frag[2] = fbf(w0.z); frag[3] = fbf(w0.w);
        frag[4] = fbf(w1.x); frag[5] = fbf(w1.y); frag[6] = fbf(w1.z); frag[7] = fbf(w1.w);
        ((bf16x8*)CB)[gi] = frag;
    } else if (blockIdx.x < 18) {
        int gi = (blockIdx.x - 8) * 256 + tid;
        if (gi >= 2560) return;
        int L = gi & 63;
        int q = gi >> 6;
        int nt = q & 3;
        int pk = q >> 2;
        int kc = pk & 1;
        int p  = pk >> 1;
        const float* Wsrc = (p == 0) ? Wsym :
                            (p == 1) ? Wsym + 4096 :
                            (p == 2) ? Wcon :
                            (p == 3) ? Wcon + 4096 : Wdis;
        int n  = nt * 16 + (L & 15);
        int kb = kc * 32 + (L >> 4) * 8;
        bf16x8 frag;
        #pragma unroll
        for (int j = 0; j < 8; j++) frag[j] = fbf(Wsrc[(kb + j) * 64 + n]);
        ((bf16x8*)WB)[gi] = frag;
    } else {
        // zero the atomic stats buffers (replaces hipMemsetAsync)
        for (int idx = tid; idx < STATSZ; idx += 256) stats[idx] = 0.f;
        // padded edge j-lists (off-diagonal union of sym+con), increasing-j
        // order; pad to 8 with a per-row sentinel j that is a non-edge in
        // BOTH planes (AAb there stays 0 -> fmaf adds exact 0).
        if (tid < N_) {
            unsigned bits = 0u;
            for (int e = 0; e < nnz_s; e++)
                if (rs[e] == tid && cs[e] != tid) bits |= 1u << cs[e];
            for (int e = 0; e < nnz_c; e++)
                if (rc[e] == tid && cc[e] != tid) bits |= 1u << cc[e];
            int cnt = 0;
            unsigned b = bits;
            while (b) { int j = __ffs(b) - 1; b &= b - 1; ej[tid * 8 + cnt++] = j; }
            int js = 0;
            while (((bits >> js) & 1u) || js == tid) js++;
            for (; cnt < 8; cnt++) ej[tid * 8 + cnt] = js;
        }
        // att A-fragments: A[m][k] = att[m][k] for m,k<22 else 0
        for (int f = tid; f < 128; f += 256) {
            int rt = f >> 6, LL = f & 63;
            int row = rt * 16 + (LL & 15);
            int kb  = (LL >> 4) * 8;
            bf16x8 frag;
            #pragma unroll
            for (int j = 0; j < 8; j++) {
                int k = kb + j;
                float vv = (row < N_ && k < N_) ? att[row * N_ + k] : 0.f;
                frag[j] = fbf(vv);
            }
            ((bf16x8*)attF)[f] = frag;
        }
    }
}

// ---------------------------------------------------------------------------
// Kernel 2: FUSED x-stage + h-GEMM + sparse mixer + z-MFMA. 1 bt per block.
// Sparse mixer now uses FIXED 8-entry padded edge lists (no data-dependent
// while loop) so all AAu loads pipeline in one latency shadow.
// ---------------------------------------------------------------------------
__launch_bounds__(256)
__global__ void fused_hmix(const float* __restrict__ x, const short* __restrict__ WB,
                           const short* __restrict__ AAb, const short* __restrict__ attF,
                           const int* __restrict__ ej, const float* __restrict__ bdis,
                           bf16* __restrict__ xs, bf16* __restrict__ yc,
                           bf16* __restrict__ z, float* __restrict__ stats1) {
    __shared__ __align__(16) char smem[14784];
    short*    xl   = (short*)smem;                 // [32][64] bf16, XOR-swizzled
    short*    dl   = (short*)(smem + 4096);
    float*    red4 = (float*)(smem + 8192);        // 512 f32 (dead before GEMM ends)
    unsigned* pp0  = (unsigned*)smem;              // [22][64] (after GEMM)
    unsigned* pp1  = (unsigned*)(smem + 5632);
    short*    p2   = (short*)(smem + 11264);       // [22][64]
    int*      ejL  = (int*)(smem + 14080);         // [22][8] edge lists
    float*    red  = (float*)smem;                 // stats scratch (post-mixing)

    const int g   = blockIdx.x;
    const int tid = threadIdx.x;
    const size_t base = (size_t)g * NO;
    const int w = tid >> 6, L = tid & 63;
    const int lane16 = L & 15, quad = L >> 4;
    const int colw = w * 16 + lane16;
    const bf16x8* WBf = (const bf16x8*)WB;

    // ---- (a) stage x + distance stats + edge-list stage
    if (tid < 176) ejL[tid] = ej[tid];
    float v[6], s = 0.f, s2 = 0.f;
    #pragma unroll
    for (int k = 0; k < 6; k++) {
        int i = w + 4 * k;
        float t = (i < N_) ? x[base + i * 64 + L] : 0.f;
        v[k] = t; s += t; s2 += t * t;
    }
    red4[w * 64 + L]       = s;
    red4[256 + w * 64 + L] = s2;
    for (int idx = tid; idx < 320; idx += 256) {   // zero pad rows 22..31
        ((unsigned*)xl)[704 + idx] = 0u;
        ((unsigned*)dl)[704 + idx] = 0u;
    }
    __syncthreads();
    float S  = (red4[L] + red4[64 + L]) + (red4[128 + L] + red4[192 + L]);
    float S2 = (red4[256 + L] + red4[320 + L]) + (red4[384 + L] + red4[448 + L]);
    #pragma unroll
    for (int k = 0; k < 6; k++) {
        int i = w + 4 * k;
        if (i < N_) {
            float t = v[k];
            float d2 = S2 - 2.f * t * S + (float)N_ * t * t;
            float d  = sqrtf(fmaxf(d2, 0.f)) + 1e-8f;
            int ci = i * 64 + (L ^ ((i & 7) << 3));
            xl[ci] = fbf(t);
            dl[ci] = fbf(d);
        }
    }
    __syncthreads();

    // ---- (b) GEMM: 5 planes x 2 row-tiles x 2 k-chunks
    f32x4 acc[5][2];
    #pragma unroll
    for (int p = 0; p < 5; p++)
        #pragma unroll
        for (int rt = 0; rt < 2; rt++) acc[p][rt] = (f32x4){0.f, 0.f, 0.f, 0.f};

    #pragma unroll
    for (int kc = 0; kc < 2; kc++) {
        bf16x8 ax[2], ad[2];
        #pragma unroll
        for (int rt = 0; rt < 2; rt++) {
            int row = rt * 16 + lane16;
            int ci  = row * 64 + ((kc * 32 + quad * 8) ^ ((row & 7) << 3));
            ax[rt] = *(const bf16x8*)(xl + ci);
            ad[rt] = *(const bf16x8*)(dl + ci);
        }
        #pragma unroll
        for (int p = 0; p < 5; p++) {
            bf16x8 bw = WBf[((p * 2 + kc) * 4 + w) * 64 + L];
            #pragma unroll
            for (int rt = 0; rt < 2; rt++) {
                bf16x8 a = (p < 4) ? ax[rt] : ad[rt];
                acc[p][rt] = __builtin_amdgcn_mfma_f32_16x16x32_bf16(a, bw, acc[p][rt], 0, 0, 0);
            }
        }
    }
    __syncthreads();   // xl/dl reads done before pp overwrite

    // ---- (c) epilogue pack -> LDS (high halves = h0: diag term = A[i,i]*h0)
    #pragma unroll
    for (int rt = 0; rt < 2; rt++)
        #pragma unroll
        for (int r = 0; r < 4; r++) {
            int m = rt * 16 + quad * 4 + r;
            if (m < N_) {
                float h0s = acc[0][rt][r], h1s = acc[1][rt][r];
                float h0c = acc[2][rt][r], h1c = acc[3][rt][r];
                pp0[m * 64 + colw] = (unsigned)(unsigned short)fbf(h1s) |
                                     ((unsigned)(unsigned short)fbf(h0s) << 16);
                pp1[m * 64 + colw] = (unsigned)(unsigned short)fbf(h1c) |
                                     ((unsigned)(unsigned short)fbf(h0c) << 16);
                p2[m * 64 + colw] = fbf(acc[4][rt][r]);
            }
        }
    __syncthreads();

    // ---- (d) z = att @ hdw via MFMA (K=32 pad, rows >=22 masked to 0)
    f32x4 zacc[2];
    zacc[0] = (f32x4){0.f, 0.f, 0.f, 0.f};
    zacc[1] = (f32x4){0.f, 0.f, 0.f, 0.f};
    {
        bf16x8 bfrag;
        #pragma unroll
        for (int j = 0; j < 8; j++) {
            int k = quad * 8 + j;
            bfrag[j] = (k < N_) ? p2[k * 64 + colw] : (short)0;
        }
        const bf16x8* attFf = (const bf16x8*)attF;
        #pragma unroll
        for (int rt = 0; rt < 2; rt++)
            zacc[rt] = __builtin_amdgcn_mfma_f32_16x16x32_bf16(attFf[rt * 64 + L], bfrag,
                                                               zacc[rt], 0, 0, 0);
    }

    // ---- (e) sparse sym/con mixing, fixed 8-entry padded edge lists
    float mxs[6], myc[6];
    #pragma unroll
    for (int k = 0; k < 6; k++) { mxs[k] = 0.f; myc[k] = 0.f; }
    const unsigned* AAu = (const unsigned*)AAb;
    #pragma unroll
    for (int k = 0; k < 6; k++) {
        int i = w + 4 * k;
        if (i < N_) {
            #pragma unroll
            for (int e = 0; e < 8; e++) {
                int j = ejL[i * 8 + e];
                unsigned a = AAu[(size_t)(i * N_ + j) * 64 + L];
                float as, ac; unp(a, as, ac);
                mxs[k] = fmaf(as, sbf((short)pp0[j * 64 + L]), mxs[k]);
                myc[k] = fmaf(ac, sbf((short)pp1[j * 64 + L]), myc[k]);
            }
        }
    }

    // ---- outputs + stats: xs/yc (channel = L); diag term = A[i,i]*h0[i]
    float st0 = 0.f, st1 = 0.f, st2 = 0.f, st3 = 0.f;
    #pragma unroll
    for (int k = 0; k < 6; k++) {
        int i = w + 4 * k;
        if (i < N_) {
            unsigned ad2 = AAu[(size_t)(i * 23) * 64 + L];
            float asd, acd; unp(ad2, asd, acd);
            float h0sv = __uint_as_float(pp0[i * 64 + L] & 0xffff0000u);
            float h0cv = __uint_as_float(pp1[i * 64 + L] & 0xffff0000u);
            float xsv = mxs[k] + asd * h0sv;
            float ycv = myc[k] + acd * h0cv;
            size_t oi = base + i * 64 + L;
            xs[oi] = f2bf(xsv); yc[oi] = f2bf(ycv);
            st0 += xsv; st1 += xsv * xsv;
            st2 += ycv; st3 += ycv * ycv;
        }
    }

    // z outputs + stats (channel = colw)
    float bd = bdis[colw];
    float st4 = 0.f, st5 = 0.f;
    #pragma unroll
    for (int rt = 0; rt < 2; rt++)
        #pragma unroll
        for (int r = 0; r < 4; r++) {
            int m = rt * 16 + quad * 4 + r;
            if (m < N_) {
                float zv = zacc[rt][r] + bd;
                z[base + (size_t)m * 64 + colw] = f2bf(zv);
                st4 += zv; st5 += zv * zv;
            }
        }
    st4 += __shfl_xor(st4, 16); st4 += __shfl_xor(st4, 32);
    st5 += __shfl_xor(st5, 16); st5 += __shfl_xor(st5, 32);

    __syncthreads();               // all pp/p2 reads done; reuse as red
    red[(w * 4 + 0) * 64 + L] = st0;
    red[(w * 4 + 1) * 64 + L] = st1;
    red[(w * 4 + 2) * 64 + L] = st2;
    red[(w * 4 + 3) * 64 + L] = st3;
    if (quad == 0) { red[16 * 64 + colw] = st4; red[17 * 64 + colw] = st5; }
    __syncthreads();
    float* myStats = stats1 + (size_t)(g & (NSHARD - 1)) * 384;
    for (int qq = tid; qq < 384; qq += 256) {
        int q = qq >> 6, o = qq & 63;
        float vv;
        if (q < 4)
            vv = (red[q * 64 + o] + red[(4 + q) * 64 + o]) +
                 (red[(8 + q) * 64 + o] + red[(12 + q) * 64 + o]);
        else
            vv = red[(12 + q) * 64 + o];   // q=4 -> row16, q=5 -> row17
        atomicAdd(&myStats[qq], vv);
    }
}

// ---------------------------------------------------------------------------
// Kernel 3: mix GEMM, 1100 blocks x 64 rows; scale1 computed in-block from
// stats1 (replaces scale_from_stats dispatch); stats2 sharded 8-way.
// ---------------------------------------------------------------------------
__launch_bounds__(256)
__global__ void mix_pass(const bf16* __restrict__ xs, const bf16* __restrict__ yc,
                         const bf16* __restrict__ z, const float* __restrict__ stats1,
                         const float* __restrict__ gammas, const float* __restrict__ betas,
                         const short* __restrict__ CB,
                         bf16* __restrict__ out2, float* __restrict__ stats2) {
    __shared__ float sL[384];
    __shared__ float red[512];

    const int tid = threadIdx.x;
    const int w = tid >> 6, L = tid & 63;
    const int lane16 = L & 15, quad = L >> 4;
    const int R0 = blockIdx.x * 64 + w * 16;

    // in-block scale1 (identical math to the old scale_from_stats, gbase=0)
    if (tid < 192) {
        int t = tid >> 6, o = tid & 63;
        float S = 0.f, SS = 0.f;
        for (int s = 0; s < NSHARD; s++) {
            S  += stats1[s * 384 + (2 * t) * 64 + o];
            SS += stats1[s * 384 + (2 * t + 1) * 64 + o];
        }
        const float invn = 1.f / (float)BTN;
        float mu   = S * invn;
        float var  = SS * invn - mu * mu;
        float rstd = rsqrtf(var + 1e-5f);
        float a = gammas[t * 64 + o] * rstd;
        float c = betas[t * 64 + o] - mu * a;
        sL[t * 128 + o]      = a;
        sL[t * 128 + 64 + o] = c;
    }
    __syncthreads();

    const bf16* srcs[3] = { xs, yc, z };

    f32x4 acc[4];
    #pragma unroll
    for (int nt = 0; nt < 4; nt++) acc[nt] = (f32x4){0.f, 0.f, 0.f, 0.f};

    #pragma unroll
    for (int kc = 0; kc < 6; kc++) {
        const int src = kc >> 1;
        const int c0  = (kc & 1) * 32 + quad * 8;
        int row = R0 + lane16;
        uint4 u = *(const uint4*)(srcs[src] + (size_t)row * 64 + c0);
        float v[8];
        unp(u.x, v[0], v[1]); unp(u.y, v[2], v[3]);
        unp(u.z, v[4], v[5]); unp(u.w, v[6], v[7]);
        bf16x8 av;
        #pragma unroll
        for (int e = 0; e < 8; e++) {
            float t = fmaxf(fmaf(v[e], sL[src * 128 + c0 + e],
                                 sL[src * 128 + 64 + c0 + e]), 0.f);
            av[e] = fbf(t);
        }
        #pragma unroll
        for (int nt = 0; nt < 4; nt++) {
            bf16x8 bw = ((const bf16x8*)CB)[(nt * 6 + kc) * 64 + L];
            acc[nt] = __builtin_amdgcn_mfma_f32_16x16x32_bf16(av, bw, acc[nt], 0, 0, 0);
        }
    }

    float s[4]  = {0.f, 0.f, 0.f, 0.f};
    float s2[4] = {0.f, 0.f, 0.f, 0.f};
    #pragma unroll
    for (int nt = 0; nt < 4; nt++)
        #pragma unroll
        for (int r = 0; r < 4; r++) {
            int row = R0 + quad * 4 + r;
            int col = nt * 16 + lane16;
            float v = acc[nt][r];
            out2[(size_t)row * 64 + col] = f2bf(v);
            s[nt] += v; s2[nt] += v * v;
        }
    #pragma unroll
    for (int nt = 0; nt < 4; nt++) {
        s[nt]  += __shfl_xor(s[nt], 16);
        s[nt]  += __shfl_xor(s[nt], 32);
        s2[nt] += __shfl_xor(s2[nt], 16);
        s2[nt] += __shfl_xor(s2[nt], 32);
    }
    if (quad == 0) {
        #pragma unroll
        for (int nt = 0; nt < 4; nt++) {
            red[w * 64 + nt * 16 + lane16]       = s[nt];
            red[256 + w * 64 + nt * 16 + lane16] = s2[nt];
        }
    }
    __syncthreads();
    float* myStats = stats2 + (size_t)(blockIdx.x & 7) * 128;
    if (tid < 64) {
        float t = red[tid] + red[64 + tid] + red[128 + tid] + red[192 + tid];
        atomicAdd(&myStats[tid], t);
    } else if (tid < 128) {
        int c = tid - 64;
        float t = red[256 + c] + red[320 + c] + red[384 + c] + red[448 + c];
        atomicAdd(&myStats[64 + c], t);
    }
}

// ---------------------------------------------------------------------------
// Kernel 4: final BN + ReLU + f32 store; scale2 computed in-block from the
// 8-sharded stats2 (replaces second scale_from_stats dispatch). 1100 blocks
// x 256 threads x 16 elems.
// ---------------------------------------------------------------------------
__launch_bounds__(256)
__global__ void final_pass(const bf16* __restrict__ out2, const float* __restrict__ stats2,
                           const float* __restrict__ gammas, const float* __restrict__ betas,
                           float* __restrict__ out) {
    __shared__ float sc[128];
    const int tid = threadIdx.x;
    if (tid < 64) {
        int o = tid;
        float S = 0.f, SS = 0.f;
        for (int s = 0; s < 8; s++) {
            S  += stats2[s * 128 + o];
            SS += stats2[s * 128 + 64 + o];
        }
        const float invn = 1.f / (float)BTN;
        float mu   = S * invn;
        float var  = SS * invn - mu * mu;
        float rstd = rsqrtf(var + 1e-5f);
        float a = gammas[192 + o] * rstd;
        float c = betas[192 + o] - mu * a;
        sc[o]      = a;
        sc[64 + o] = c;
    }
    __syncthreads();
    #pragma unroll
    for (int j = 0; j < 4; j++) {
        int gid = blockIdx.x * 1024 + j * 256 + tid;   // float4 index
        ushort4 u = reinterpret_cast<const ushort4*>(out2)[gid];
        const int o = (gid * 4) & 63;
        float f0, f1, f2, f3;
        unp((unsigned)u.x | ((unsigned)u.y << 16), f0, f1);
        unp((unsigned)u.z | ((unsigned)u.w << 16), f2, f3);
        float4 r;
        r.x = fmaxf(fmaf(f0, sc[o],     sc[64 + o]),     0.f);
        r.y = fmaxf(fmaf(f1, sc[o + 1], sc[64 + o + 1]), 0.f);
        r.z = fmaxf(fmaf(f2, sc[o + 2], sc[64 + o + 2]), 0.f);
        r.w = fmaxf(fmaf(f3, sc[o + 3], sc[64 + o + 3]), 0.f);
        reinterpret_cast<float4*>(out)[gid] = r;
    }
}

// ---------------------------------------------------------------------------
extern "C" void kernel_launch(void* const* d_in, const int* in_sizes, int n_in,
                              void* d_out, int out_size, void* d_ws, size_t ws_size,
                              hipStream_t stream) {
    const float* x      = (const float*)d_in[0];
    const float* W_sym  = (const float*)d_in[1];
    const float* e_sym  = (const float*)d_in[2];
    const float* W_con  = (const float*)d_in[3];
    const float* e_con  = (const float*)d_in[4];
    const float* W_dis  = (const float*)d_in[5];
    const float* att    = (const float*)d_in[6];
    const float* b_dis  = (const float*)d_in[7];
    const float* cat_w  = (const float*)d_in[8];
    const float* gammas = (const float*)d_in[9];
    const float* betas  = (const float*)d_in[10];
    const int* rows_sym = (const int*)d_in[11];
    const int* cols_sym = (const int*)d_in[12];
    const int* rows_con = (const int*)d_in[13];
    const int* cols_con = (const int*)d_in[14];
    const int nnz_s = in_sizes[2] / 64;
    const int nnz_c = in_sizes[4] / 64;

    char* p = (char*)d_ws;
    float* stats  = (float*)p; p += (size_t)STATSZ * 4;
    short* AAb    = (short*)p; p += (size_t)NN * 64 * 2 * 2;
    short* CB     = (short*)p; p += (size_t)1536 * 8 * 2;
    short* WB     = (short*)p; p += (size_t)2560 * 8 * 2;
    int*   ej     = (int*)p;   p += 192 * 4;
    short* attF   = (short*)p; p += 128 * 16;
    bf16*  xsb    = (bf16*)p;  p += (size_t)ELEMS * 2;
    bf16*  ycb    = (bf16*)p;  p += (size_t)ELEMS * 2;
    bf16*  zb     = (bf16*)p;  p += (size_t)ELEMS * 2;
    bf16*  out2   = (bf16*)p;  p += (size_t)ELEMS * 2;
    float* stats1 = stats;
    float* stats2 = stats + NSHARD * 384;

    hipMemsetAsync(AAb, 0, (size_t)NN * 64 * 2 * 2, stream);
    prep_kernel<<<19, 256, 0, stream>>>(e_sym, rows_sym, cols_sym, nnz_s,
                                        e_con, rows_con, cols_con, nnz_c,
                                        cat_w, W_sym, W_con, W_dis, att,
                                        AAb, CB, WB, ej, attF, stats);
    fused_hmix<<<BT, 256, 0, stream>>>(x, WB, AAb, attF, ej, b_dis,
                                       xsb, ycb, zb, stats1);
    mix_pass<<<1100, 256, 0, stream>>>(xsb, ycb, zb, stats1, gammas, betas,
                                       CB, out2, stats2);
    final_pass<<<1100, 256, 0, stream>>>(out2, stats2, gammas, betas, (float*)d_out);
}